// Round 1
// baseline (2271.834 us; speedup 1.0000x reference)
//
#include <hip/hip_runtime.h>
#include <hip/hip_bf16.h>

// SLSTM (plain LSTM recurrence) + final Linear.
// B=1024, T=2048, IN=16, H=128, OUT=1.
// Persistent kernel: 64 WGs x 512 threads; WG owns 16 batch rows for all T steps.
// gates = [h | x_t | pad] (K=160) @ [W_hh | W_ih | 0]^T via mfma_f32_16x16x32_bf16.
// Wave w owns N-tiles {w, w+8, w+16, w+24} = i,f,g,o for the same h-columns ->
// elementwise update + c state fully in registers. h double-buffered in LDS (bf16).

#define T_LEN 2048
#define IN_DIM 16
#define H_DIM 128

typedef __attribute__((ext_vector_type(4))) float f32x4;
typedef __attribute__((ext_vector_type(8))) short s16x8;

__device__ __forceinline__ short f2bf(float f) {
    union { float f; unsigned u; } v; v.f = f;
    unsigned r = v.u + 0x7fffu + ((v.u >> 16) & 1u);   // RNE
    return (short)(r >> 16);
}
__device__ __forceinline__ float sigf(float x) {
    // 1/(1+2^(-x*log2e)); large |x| saturates correctly through v_exp/v_rcp
    return __builtin_amdgcn_rcpf(1.0f + __builtin_amdgcn_exp2f(-1.442695041f * x));
}
__device__ __forceinline__ float tanh_fast(float x) {
    float xc = fminf(fmaxf(x, -15.0f), 15.0f);         // avoid inf/inf
    float e  = __builtin_amdgcn_exp2f(2.885390082f * xc);
    return (e - 1.0f) * __builtin_amdgcn_rcpf(e + 1.0f);
}

__global__ __launch_bounds__(512, 2)
void slstm_persistent(const float* __restrict__ x,
                      const float* __restrict__ W_ih,
                      const float* __restrict__ W_hh,
                      const float* __restrict__ b_ih,
                      const float* __restrict__ b_hh,
                      const float* __restrict__ fc_w,
                      const float* __restrict__ fc_b,
                      float* __restrict__ out)
{
    // h tiles: 16 rows x 128 cols bf16, row stride 136 (pad 8 -> 2-way banks max)
    __shared__ unsigned short h_lds[2][16][136];
    __shared__ float red[16];

    const int tid  = threadIdx.x;
    const int lane = tid & 63;
    const int wv   = tid >> 6;          // wave 0..7
    const int c16  = lane & 15;         // n-within-tile / A-row (batch row)
    const int quad = lane >> 4;         // 0..3
    const int b0   = blockIdx.x * 16;

    // ---- W' = [W_hh | W_ih | 0] fragments (B-operand: lane holds B[k=quad*8+j][n=c16]) ----
    s16x8 bfrag[4][5];
    float sbias[4];
    #pragma unroll
    for (int g = 0; g < 4; ++g) {
        const int n = g * 128 + wv * 16 + c16;          // global gate index
        sbias[g] = b_ih[n] + b_hh[n];
        #pragma unroll
        for (int kf = 0; kf < 5; ++kf) {
            s16x8 fr;
            #pragma unroll
            for (int j = 0; j < 8; ++j) {
                const int k = kf * 32 + quad * 8 + j;   // 0..159
                float v;
                if (kf < 4) {
                    v = W_hh[n * H_DIM + k];
                } else {
                    const int kk = k - H_DIM;           // 0..31
                    v = (kk < IN_DIM) ? W_ih[n * IN_DIM + kk] : 0.0f;
                }
                fr[j] = f2bf(v);
            }
            bfrag[g][kf] = fr;
        }
    }

    // ---- init h0 = 0 in both LDS buffers ----
    for (int i = tid; i < 2 * 16 * 136; i += 512)
        ((unsigned short*)h_lds)[i] = 0;

    float c_st[4] = {0.f, 0.f, 0.f, 0.f};
    float hreg[4] = {0.f, 0.f, 0.f, 0.f};

    // ---- x prefetch (t=0). Lane loads x[b0+c16][t][q01*8 .. q01*8+7] ----
    const float* xrow = x + (size_t)(b0 + c16) * (size_t)(T_LEN * IN_DIM);
    const int q01 = quad & 1;
    f32x4 px0 = *(const f32x4*)(xrow + q01 * 8);
    f32x4 px1 = *(const f32x4*)(xrow + q01 * 8 + 4);

    __syncthreads();

    for (int t = 0; t < T_LEN; ++t) {
        const int buf = t & 1;

        // A-frags: h from LDS (4 x ds_read_b128), then x frag from prefetch regs
        s16x8 af[5];
        #pragma unroll
        for (int kf = 0; kf < 4; ++kf)
            af[kf] = *(const s16x8*)&h_lds[buf][c16][kf * 32 + quad * 8];
        {
            s16x8 xf;
            #pragma unroll
            for (int j = 0; j < 4; ++j) {
                xf[j]     = (quad < 2) ? f2bf(px0[j]) : (short)0;
                xf[j + 4] = (quad < 2) ? f2bf(px1[j]) : (short)0;
            }
            af[4] = xf;
        }

        // prefetch next timestep (clamped; hidden behind MFMAs)
        const int tn = (t + 1 < T_LEN) ? (t + 1) : (T_LEN - 1);
        px0 = *(const f32x4*)(xrow + tn * IN_DIM + q01 * 8);
        px1 = *(const f32x4*)(xrow + tn * IN_DIM + q01 * 8 + 4);

        // gates: acc[g] = bias + [h|x|0] @ W'^T  -- 20 MFMAs, 4 independent chains
        f32x4 acc[4];
        #pragma unroll
        for (int g = 0; g < 4; ++g) {
            f32x4 a; a[0] = sbias[g]; a[1] = sbias[g]; a[2] = sbias[g]; a[3] = sbias[g];
            acc[g] = a;
        }
        #pragma unroll
        for (int kf = 0; kf < 5; ++kf)
            #pragma unroll
            for (int g = 0; g < 4; ++g)
                acc[g] = __builtin_amdgcn_mfma_f32_16x16x32_bf16(af[kf], bfrag[g][kf], acc[g], 0, 0, 0);

        // elementwise LSTM update, all in registers (C/D: row=quad*4+r, col=wv*16+c16)
        #pragma unroll
        for (int r = 0; r < 4; ++r) {
            const float ig = acc[0][r], fg = acc[1][r], gg = acc[2][r], og = acc[3][r];
            const float cn = sigf(fg) * c_st[r] + sigf(ig) * tanh_fast(gg);
            c_st[r] = cn;
            const float hn = sigf(og) * tanh_fast(cn);
            hreg[r] = hn;
            h_lds[buf ^ 1][quad * 4 + r][wv * 16 + c16] = (unsigned short)f2bf(hn);
        }
        __syncthreads();
    }

    // ---- epilogue: out[b] = h_final[b] . fc_w + fc_b ----
    if (tid < 16) red[tid] = 0.0f;
    __syncthreads();
    const float fcw = fc_w[wv * 16 + c16];
    #pragma unroll
    for (int r = 0; r < 4; ++r) {
        float v = hreg[r] * fcw;            // lane owns h[quad*4+r][wv*16+c16]
        v += __shfl_xor(v, 1);
        v += __shfl_xor(v, 2);
        v += __shfl_xor(v, 4);
        v += __shfl_xor(v, 8);              // sum over 16 col-lanes of this quad
        if (c16 == 0) atomicAdd(&red[quad * 4 + r], v);
    }
    __syncthreads();
    if (tid < 16) out[b0 + tid] = red[tid] + fc_b[0];
}

extern "C" void kernel_launch(void* const* d_in, const int* in_sizes, int n_in,
                              void* d_out, int out_size, void* d_ws, size_t ws_size,
                              hipStream_t stream) {
    const float* x    = (const float*)d_in[0];
    const float* W_ih = (const float*)d_in[1];
    const float* W_hh = (const float*)d_in[2];
    const float* b_ih = (const float*)d_in[3];
    const float* b_hh = (const float*)d_in[4];
    const float* fc_w = (const float*)d_in[5];
    const float* fc_b = (const float*)d_in[6];
    float* out = (float*)d_out;

    slstm_persistent<<<64, 512, 0, stream>>>(x, W_ih, W_hh, b_ih, b_hh, fc_w, fc_b, out);
}